// Round 2
// baseline (178.542 us; speedup 1.0000x reference)
//
#include <hip/hip_runtime.h>
#include <hip/hip_bf16.h>

typedef unsigned short u16;
typedef unsigned int u32;

#define TT 192
#define BB 2
#define HH 8
#define DD 64
#define CC 512
#define MM (BB*TT)   // 384

// ws layout (u16 elements): Q,K0,K1,V0,V1 each [bh][t][d], then ATT [m][c]
#define TSZ   ((size_t)MM * CC)
#define OFF_ATT (5 * TSZ)

typedef short bf16x8 __attribute__((ext_vector_type(8)));
typedef float f32x4  __attribute__((ext_vector_type(4)));

union FragU { uint4 u; bf16x8 b; };

// Raw HW transcendentals (r13-verified: VALUBusy 58->27%): one v_exp_f32 /
// v_rcp_f32 instead of guarded libm sequences. ~1ulp, irrelevant vs 2% tol.
#if __has_builtin(__builtin_amdgcn_exp2f)
#define EXP2F(x) __builtin_amdgcn_exp2f(x)
#else
#define EXP2F(x) exp2f(x)
#endif
#if __has_builtin(__builtin_amdgcn_rcpf)
#define RCPF(x) __builtin_amdgcn_rcpf(x)
#else
#define RCPF(x) (1.f / (x))
#endif

__device__ __forceinline__ float bf2f(u16 u) {
    return __uint_as_float(((u32)u) << 16);
}
__device__ __forceinline__ u16 f2bf(float f) {
    u32 u = __float_as_uint(f);
    u32 r = u + 0x7FFFu + ((u >> 16) & 1u);   // RNE
    return (u16)(r >> 16);
}
// pack hi16(a),hi16(b) -> one u32 (truncation round; bias cancels in P/Z)
__device__ __forceinline__ u32 trunc_pk(u32 b_hi, u32 a_lo) {
    return __builtin_amdgcn_perm(b_hi, a_lo, 0x07060302u);
}

// dtype detect: 1 load + ballot. bf16 data => low u16 exponent near 127.
__device__ __forceinline__ u32 detect_bf16_fast(const u32* __restrict__ x) {
    const int lane = threadIdx.x & 63;
    u32 v = x[lane & 31];
    u32 e = (v >> 7) & 0xFF;
    unsigned long long m = __ballot(e >= 113 && e <= 133);
    return (__popcll(m) >= 32) ? 1u : 0u;
}

// dtype-aware 16-element load (two uint4 of packed bf16)
__device__ __forceinline__ void ld16(const void* __restrict__ base, size_t off, u32 fl,
                                     uint4& lo, uint4& hi) {
    if (fl) {
        const uint4* p = (const uint4*)((const u16*)base + off);
        lo = p[0]; hi = p[1];
    } else {
        const float* s = (const float*)base + off;
        float4 f0 = *(const float4*)(s);
        float4 f1 = *(const float4*)(s + 4);
        float4 f2 = *(const float4*)(s + 8);
        float4 f3 = *(const float4*)(s + 12);
        lo = make_uint4((u32)f2bf(f0.x) | ((u32)f2bf(f0.y) << 16),
                        (u32)f2bf(f0.z) | ((u32)f2bf(f0.w) << 16),
                        (u32)f2bf(f1.x) | ((u32)f2bf(f1.y) << 16),
                        (u32)f2bf(f1.z) | ((u32)f2bf(f1.w) << 16));
        hi = make_uint4((u32)f2bf(f2.x) | ((u32)f2bf(f2.y) << 16),
                        (u32)f2bf(f2.z) | ((u32)f2bf(f2.w) << 16),
                        (u32)f2bf(f3.x) | ((u32)f2bf(f3.y) << 16),
                        (u32)f2bf(f3.z) | ((u32)f2bf(f3.w) << 16));
    }
}

// ---------------------------------------------------------------------------
// LDS-staged MFMA projection GEMM (r9-verified): out = A @ W^T + bias.
// 64x64 tile, 4 waves, BK=64, coalesced 128B staging, stride-72 LDS,
// register prefetch of step k+1.
// ---------------------------------------------------------------------------
__device__ __forceinline__ void proj_lds(const void* __restrict__ A, u32 aFl,
                                         const void* __restrict__ W,
                                         const void* __restrict__ bias, u32 wFl,
                                         void* __restrict__ out, int headperm, u32 outFl) {
    __shared__ __align__(16) u16 As[64][72];
    __shared__ __align__(16) u16 Ws[64][72];
    const int tid = threadIdx.x;
    const int w = tid >> 6, lane = tid & 63;
    const int quad = lane >> 4, li = lane & 15;
    const int mb = blockIdx.y * 64, nb = blockIdx.x * 64;

    const int r = tid >> 2;
    const int c = (tid & 3) * 16;

    const size_t abase = (size_t)(mb + r) * CC + c;
    const size_t wbase = (size_t)(nb + r) * CC + c;

    f32x4 acc[4];
#pragma unroll
    for (int ct = 0; ct < 4; ct++) acc[ct] = (f32x4){0.f, 0.f, 0.f, 0.f};

    uint4 a0, a1, w0, w1;
    ld16(A, abase, aFl, a0, a1);
    ld16(W, wbase, wFl, w0, w1);

#pragma unroll
    for (int step = 0; step < 8; step++) {
        *(uint4*)&As[r][c] = a0; *(uint4*)&As[r][c + 8] = a1;
        *(uint4*)&Ws[r][c] = w0; *(uint4*)&Ws[r][c + 8] = w1;
        __syncthreads();
        if (step < 7) {
            const int kb = (step + 1) * 64;
            ld16(A, abase + kb, aFl, a0, a1);
            ld16(W, wbase + kb, wFl, w0, w1);
        }
#pragma unroll
        for (int kk = 0; kk < 2; kk++) {
            FragU af; af.u = *(const uint4*)&As[w * 16 + li][kk * 32 + quad * 8];
#pragma unroll
            for (int ct = 0; ct < 4; ct++) {
                FragU wf; wf.u = *(const uint4*)&Ws[ct * 16 + li][kk * 32 + quad * 8];
                acc[ct] = __builtin_amdgcn_mfma_f32_16x16x32_bf16(af.b, wf.b, acc[ct], 0, 0, 0);
            }
        }
        __syncthreads();
    }

#pragma unroll
    for (int ct = 0; ct < 4; ct++) {
        const int n = nb + ct * 16 + li;
        const float bv = wFl ? bf2f(((const u16*)bias)[n]) : ((const float*)bias)[n];
#pragma unroll
        for (int rr = 0; rr < 4; rr++) {
            const int m = mb + w * 16 + quad * 4 + rr;
            const float v = acc[ct][rr] + bv;
            if (headperm) {
                const int b = (m >= TT) ? 1 : 0;
                const int tloc = m - b * TT;
                ((u16*)out)[((size_t)(b * HH + (n >> 6)) * TT + tloc) * DD + (n & 63)] = f2bf(v);
            } else {
                if (outFl) ((u16*)out)[(size_t)m * CC + n] = f2bf(v);
                else       ((float*)out)[(size_t)m * CC + n] = v;
            }
        }
    }
}

__global__ __launch_bounds__(256) void proj5_kernel(
    const void* __restrict__ x,
    const void* __restrict__ Wq,  const void* __restrict__ bq,
    const void* __restrict__ Wk0, const void* __restrict__ bk0,
    const void* __restrict__ Wk1, const void* __restrict__ bk1,
    const void* __restrict__ Wv0, const void* __restrict__ bv0,
    const void* __restrict__ Wv1, const void* __restrict__ bv1,
    u16* __restrict__ ws16) {
    const u32 fl = detect_bf16_fast((const u32*)x);
    const int z = blockIdx.z;
    const void* W; const void* bi;
    switch (z) {
        case 0:  W = Wq;  bi = bq;  break;
        case 1:  W = Wk0; bi = bk0; break;
        case 2:  W = Wk1; bi = bk1; break;
        case 3:  W = Wv0; bi = bv0; break;
        default: W = Wv1; bi = bv1; break;
    }
    proj_lds(x, fl, W, bi, fl, (void*)(ws16 + (size_t)z * TSZ), 1, 1u);
}

__global__ __launch_bounds__(256) void projo_kernel(const u16* __restrict__ ws16,
                                                    const void* __restrict__ Wo,
                                                    const void* __restrict__ bo,
                                                    void* __restrict__ out,
                                                    const void* __restrict__ xorig) {
    const u32 fl = detect_bf16_fast((const u32*)xorig);
    proj_lds(ws16 + OFF_ATT, 1u, Wo, bo, fl, out, 0, fl);
}

// ---------------------------------------------------------------------------
// MFMA attention, r15: register-occupancy attack.
// r14 removed the P LDS round-trip (bank conflicts 3.8M->1.18M, LDS ->25600)
// but occupancy stayed pinned at 28.5% -> the binding limit is the unified
// VGPR/AGPR file (~150-170 regs/wave with 48-l-per-wave state = 2-3
// waves/SIMD). Fix: 6 waves x 32 l-rows each (384-thread block, rt<2):
// Wacc 48->32, Zacc 12->8, afr 24->16, a2 12->8 regs; peak live ~100.
// __launch_bounds__(384,4) holds allocation <=128 -> 4+ waves/SIMD.
// Per-wave exp/epilogue VALU also drops 33% (same aggregate).
// Everything else (register-resident P via m-permutation folded into v1t
// staging, barrier-free mt loop, swizzled v1t) is r14-identical.
// LDS 25600B: v1t [64 d][200] swz; epilogue osum (1.5KB) overlays after bar.
// ---------------------------------------------------------------------------
__global__ __launch_bounds__(384, 4) void attn_kernel(u16* __restrict__ ws16) {
    __shared__ __align__(16) u16 smem[12800];   // 25600 B
    const int tid = threadIdx.x;
    const int w = tid >> 6, lane = tid & 63;
    const int quad = lane >> 4, li = lane & 15;
    const int k = blockIdx.x, bh = blockIdx.y;

    const u16* qg  = ws16 + ((size_t)bh * TT + k) * DD;
    const u16* k0g = ws16 + TSZ     + (size_t)bh * TT * DD;
    const u16* k1g = ws16 + 2 * TSZ + (size_t)bh * TT * DD;
    const u16* v0g = ws16 + 3 * TSZ + (size_t)bh * TT * DD;
    const u16* v1g = ws16 + 4 * TSZ + (size_t)bh * TT * DD;

    // ---- stage v1^T (stride 200, conflict swz (pos>>3)^(d>>3)) with the
    //      K-slot permutation folded into the row->position map ----
    //      v1 row m -> pos = (m&~31) | {m3,m2,m4,m1,m0}
#pragma unroll
    for (int it = 0; it < 4; it++) {
        const int flat = (it * 384 + tid) * 8;
        const int row = flat >> 6, c0 = flat & 63;   // row=m, c0=d base
        uint4 b = *(const uint4*)(v1g + flat);
        u16 vb[8]; *(uint4*)vb = b;
        const int w5 = row & 31;
        const int pos = (row & ~31) | ((w5 & 12) << 1) | ((w5 >> 4) << 2) | (w5 & 3);
        const int swz = (((pos >> 3) ^ (c0 >> 3)) << 3) | (pos & 7);
#pragma unroll
        for (int j = 0; j < 8; j++)
            smem[(c0 + j) * 200 + swz] = vb[j];
    }

    // ---- afr: a[l,d] = bf16_trunc(scl*q[d]*k0[l,d]), scl=0.125*log2e ----
    FragU afr[2][2];
#pragma unroll
    for (int kk = 0; kk < 2; kk++) {
        uint4 qu = *(const uint4*)(qg + kk * 32 + quad * 8);
        u16 qv[8]; *(uint4*)qv = qu;
        float qf[8];
#pragma unroll
        for (int j = 0; j < 8; j++) qf[j] = bf2f(qv[j]) * 0.18033688f;
#pragma unroll
        for (int rt = 0; rt < 2; rt++) {
            uint4 ku = *(const uint4*)(k0g + (size_t)(w * 32 + rt * 16 + li) * DD + kk * 32 + quad * 8);
            u16 kv[8]; *(uint4*)kv = ku;
            u32 pk[4];
#pragma unroll
            for (int p = 0; p < 4; p++) {
                u32 lo = __float_as_uint(qf[2 * p] * bf2f(kv[2 * p]));
                u32 hi = __float_as_uint(qf[2 * p + 1] * bf2f(kv[2 * p + 1]));
                pk[p] = trunc_pk(hi, lo);
            }
            afr[rt][kk].u = make_uint4(pk[0], pk[1], pk[2], pk[3]);
        }
    }

    FragU ones;
    ones.u = make_uint4(0x3F803F80u, 0x3F803F80u, 0x3F803F80u, 0x3F803F80u);

    f32x4 Wacc[2][4], Zacc[2];
#pragma unroll
    for (int rt = 0; rt < 2; rt++) {
        Zacc[rt] = (f32x4){0.f, 0.f, 0.f, 0.f};
#pragma unroll
        for (int cd = 0; cd < 4; cd++) Wacc[rt][cd] = (f32x4){0.f, 0.f, 0.f, 0.f};
    }

    __syncthreads();   // v1t staged

    // ---- m-tile loop (6 x 32), barrier-free, no LDS writes ----
    for (int mt = 0; mt < 6; mt++) {
        FragU a2[2];
        // GEMM1 (transposed) + v_exp_f32, packed straight into A-frags
#pragma unroll
        for (int ct = 0; ct < 2; ct++) {
            const u16* krow = k1g + (size_t)(mt * 32 + ct * 16 + li) * DD + quad * 8;
            FragU kf0, kf1;
            kf0.u = *(const uint4*)(krow);
            kf1.u = *(const uint4*)(krow + 32);
#pragma unroll
            for (int rt = 0; rt < 2; rt++) {
                f32x4 acc = (f32x4){0.f, 0.f, 0.f, 0.f};
                acc = __builtin_amdgcn_mfma_f32_16x16x32_bf16(kf0.b, afr[rt][0].b, acc, 0, 0, 0);
                acc = __builtin_amdgcn_mfma_f32_16x16x32_bf16(kf1.b, afr[rt][1].b, acc, 0, 0, 0);
                const u32 lo = trunc_pk(__float_as_uint(EXP2F(acc[1])), __float_as_uint(EXP2F(acc[0])));
                const u32 hi = trunc_pk(__float_as_uint(EXP2F(acc[3])), __float_as_uint(EXP2F(acc[2])));
                if (ct == 0) { a2[rt].u.x = lo; a2[rt].u.y = hi; }
                else         { a2[rt].u.z = lo; a2[rt].u.w = hi; }
            }
        }
        // GEMM2 + Z on MFMA pipe (B-frags b128 from swizzled v1t; independent
        // of the GEMM1->exp chain, scheduler free to hoist)
        FragU b2[4];
#pragma unroll
        for (int cd = 0; cd < 4; cd++) {
            const int d = cd * 16 + li;
            b2[cd].u = *(const uint4*)(smem + d * 200 + (((mt * 4 + quad) ^ (d >> 3)) << 3));
        }
#pragma unroll
        for (int rt = 0; rt < 2; rt++) {
            Zacc[rt] = __builtin_amdgcn_mfma_f32_16x16x32_bf16(a2[rt].b, ones.b, Zacc[rt], 0, 0, 0);
#pragma unroll
            for (int cd = 0; cd < 4; cd++)
                Wacc[rt][cd] = __builtin_amdgcn_mfma_f32_16x16x32_bf16(a2[rt].b, b2[cd].b, Wacc[rt][cd], 0, 0, 0);
        }
    }

    __syncthreads();   // all waves done with v1t (osum overlays it)

    // ---- epilogue: v0 from global, per-rt to cap live VGPRs ----
    float op[4] = {0.f, 0.f, 0.f, 0.f};
#pragma unroll
    for (int rt = 0; rt < 2; rt++) {
        float v0v[4][4];
#pragma unroll
        for (int r = 0; r < 4; r++) {
            const int l = w * 32 + rt * 16 + quad * 4 + r;
#pragma unroll
            for (int cd = 0; cd < 4; cd++)
                v0v[r][cd] = bf2f(v0g[(size_t)l * DD + cd * 16 + li]);
        }
#pragma unroll
        for (int r = 0; r < 4; r++) {
            const float iv = RCPF(Zacc[rt][r]);
#pragma unroll
            for (int cd = 0; cd < 4; cd++)
                op[cd] = fmaf(v0v[r][cd] * iv, Wacc[rt][cd][r], op[cd]);
        }
    }
#pragma unroll
    for (int cd = 0; cd < 4; cd++) {
        op[cd] += __shfl_xor(op[cd], 16);
        op[cd] += __shfl_xor(op[cd], 32);
    }
    float* osum = (float*)smem;
    if (quad == 0) {
#pragma unroll
        for (int cd = 0; cd < 4; cd++) osum[w * 64 + cd * 16 + li] = op[cd];
    }
    __syncthreads();
    if (tid < DD) {
        const float o = osum[tid] + osum[64 + tid] + osum[128 + tid] +
                        osum[192 + tid] + osum[256 + tid] + osum[320 + tid];
        const int b = bh >> 3, h = bh & 7;
        u16* ATT = ws16 + OFF_ATT;
        ATT[((size_t)(b * TT + k)) * CC + h * DD + tid] = f2bf(o);
    }
}

extern "C" void kernel_launch(void* const* d_in, const int* in_sizes, int n_in,
                              void* d_out, int out_size, void* d_ws, size_t ws_size,
                              hipStream_t stream) {
    u16* ws16 = (u16*)d_ws;

    dim3 gp(CC / 64, MM / 64, 5);   // 8 x 6 x 5
    proj5_kernel<<<gp, 256, 0, stream>>>(
        d_in[0], d_in[1], d_in[2], d_in[3], d_in[4], d_in[5], d_in[6],
        d_in[7], d_in[8], d_in[9], d_in[10], ws16);

    dim3 ga(TT, BB * HH);           // 192 x 16, one k per block
    attn_kernel<<<ga, 384, 0, stream>>>(ws16);

    dim3 go(CC / 64, MM / 64, 1);   // 8 x 6
    projo_kernel<<<go, 256, 0, stream>>>(ws16, d_in[11], d_in[12], d_out, d_in[0]);
}

// Round 3
// 154.186 us; speedup vs baseline: 1.1580x; 1.1580x over previous
//
#include <hip/hip_runtime.h>
#include <hip/hip_bf16.h>

typedef unsigned short u16;
typedef unsigned int u32;

#define TT 192
#define BB 2
#define HH 8
#define DD 64
#define CC 512
#define MM (BB*TT)   // 384

// ws layout (u16 elements): Q,K0,K1,V0,V1 each [bh][t][d], then ATT [m][c]
#define TSZ   ((size_t)MM * CC)
#define OFF_ATT (5 * TSZ)

typedef short bf16x8 __attribute__((ext_vector_type(8)));
typedef float f32x4  __attribute__((ext_vector_type(4)));

union FragU { uint4 u; bf16x8 b; };

// Raw HW transcendentals (r13-verified: VALUBusy 58->27%): one v_exp_f32 /
// v_rcp_f32 instead of guarded libm sequences. ~1ulp, irrelevant vs 2% tol.
#if __has_builtin(__builtin_amdgcn_exp2f)
#define EXP2F(x) __builtin_amdgcn_exp2f(x)
#else
#define EXP2F(x) exp2f(x)
#endif
#if __has_builtin(__builtin_amdgcn_rcpf)
#define RCPF(x) __builtin_amdgcn_rcpf(x)
#else
#define RCPF(x) (1.f / (x))
#endif

__device__ __forceinline__ float bf2f(u16 u) {
    return __uint_as_float(((u32)u) << 16);
}
__device__ __forceinline__ u16 f2bf(float f) {
    u32 u = __float_as_uint(f);
    u32 r = u + 0x7FFFu + ((u >> 16) & 1u);   // RNE
    return (u16)(r >> 16);
}
// pack hi16(a),hi16(b) -> one u32 (truncation round; bias cancels in P/Z)
__device__ __forceinline__ u32 trunc_pk(u32 b_hi, u32 a_lo) {
    return __builtin_amdgcn_perm(b_hi, a_lo, 0x07060302u);
}

// dtype detect: 1 load + ballot. bf16 data => low u16 exponent near 127.
__device__ __forceinline__ u32 detect_bf16_fast(const u32* __restrict__ x) {
    const int lane = threadIdx.x & 63;
    u32 v = x[lane & 31];
    u32 e = (v >> 7) & 0xFF;
    unsigned long long m = __ballot(e >= 113 && e <= 133);
    return (__popcll(m) >= 32) ? 1u : 0u;
}

// dtype-aware 16-element load (two uint4 of packed bf16)
__device__ __forceinline__ void ld16(const void* __restrict__ base, size_t off, u32 fl,
                                     uint4& lo, uint4& hi) {
    if (fl) {
        const uint4* p = (const uint4*)((const u16*)base + off);
        lo = p[0]; hi = p[1];
    } else {
        const float* s = (const float*)base + off;
        float4 f0 = *(const float4*)(s);
        float4 f1 = *(const float4*)(s + 4);
        float4 f2 = *(const float4*)(s + 8);
        float4 f3 = *(const float4*)(s + 12);
        lo = make_uint4((u32)f2bf(f0.x) | ((u32)f2bf(f0.y) << 16),
                        (u32)f2bf(f0.z) | ((u32)f2bf(f0.w) << 16),
                        (u32)f2bf(f1.x) | ((u32)f2bf(f1.y) << 16),
                        (u32)f2bf(f1.z) | ((u32)f2bf(f1.w) << 16));
        hi = make_uint4((u32)f2bf(f2.x) | ((u32)f2bf(f2.y) << 16),
                        (u32)f2bf(f2.z) | ((u32)f2bf(f2.w) << 16),
                        (u32)f2bf(f3.x) | ((u32)f2bf(f3.y) << 16),
                        (u32)f2bf(f3.z) | ((u32)f2bf(f3.w) << 16));
    }
}

// ---------------------------------------------------------------------------
// LDS-staged MFMA projection GEMM (r9-verified): out = A @ W^T + bias.
// 64x64 tile, 4 waves, BK=64, coalesced 128B staging, stride-72 LDS,
// register prefetch of step k+1.
// ---------------------------------------------------------------------------
__device__ __forceinline__ void proj_lds(const void* __restrict__ A, u32 aFl,
                                         const void* __restrict__ W,
                                         const void* __restrict__ bias, u32 wFl,
                                         void* __restrict__ out, int headperm, u32 outFl) {
    __shared__ __align__(16) u16 As[64][72];
    __shared__ __align__(16) u16 Ws[64][72];
    const int tid = threadIdx.x;
    const int w = tid >> 6, lane = tid & 63;
    const int quad = lane >> 4, li = lane & 15;
    const int mb = blockIdx.y * 64, nb = blockIdx.x * 64;

    const int r = tid >> 2;
    const int c = (tid & 3) * 16;

    const size_t abase = (size_t)(mb + r) * CC + c;
    const size_t wbase = (size_t)(nb + r) * CC + c;

    f32x4 acc[4];
#pragma unroll
    for (int ct = 0; ct < 4; ct++) acc[ct] = (f32x4){0.f, 0.f, 0.f, 0.f};

    uint4 a0, a1, w0, w1;
    ld16(A, abase, aFl, a0, a1);
    ld16(W, wbase, wFl, w0, w1);

#pragma unroll
    for (int step = 0; step < 8; step++) {
        *(uint4*)&As[r][c] = a0; *(uint4*)&As[r][c + 8] = a1;
        *(uint4*)&Ws[r][c] = w0; *(uint4*)&Ws[r][c + 8] = w1;
        __syncthreads();
        if (step < 7) {
            const int kb = (step + 1) * 64;
            ld16(A, abase + kb, aFl, a0, a1);
            ld16(W, wbase + kb, wFl, w0, w1);
        }
#pragma unroll
        for (int kk = 0; kk < 2; kk++) {
            FragU af; af.u = *(const uint4*)&As[w * 16 + li][kk * 32 + quad * 8];
#pragma unroll
            for (int ct = 0; ct < 4; ct++) {
                FragU wf; wf.u = *(const uint4*)&Ws[ct * 16 + li][kk * 32 + quad * 8];
                acc[ct] = __builtin_amdgcn_mfma_f32_16x16x32_bf16(af.b, wf.b, acc[ct], 0, 0, 0);
            }
        }
        __syncthreads();
    }

#pragma unroll
    for (int ct = 0; ct < 4; ct++) {
        const int n = nb + ct * 16 + li;
        const float bv = wFl ? bf2f(((const u16*)bias)[n]) : ((const float*)bias)[n];
#pragma unroll
        for (int rr = 0; rr < 4; rr++) {
            const int m = mb + w * 16 + quad * 4 + rr;
            const float v = acc[ct][rr] + bv;
            if (headperm) {
                const int b = (m >= TT) ? 1 : 0;
                const int tloc = m - b * TT;
                ((u16*)out)[((size_t)(b * HH + (n >> 6)) * TT + tloc) * DD + (n & 63)] = f2bf(v);
            } else {
                if (outFl) ((u16*)out)[(size_t)m * CC + n] = f2bf(v);
                else       ((float*)out)[(size_t)m * CC + n] = v;
            }
        }
    }
}

__global__ __launch_bounds__(256) void proj5_kernel(
    const void* __restrict__ x,
    const void* __restrict__ Wq,  const void* __restrict__ bq,
    const void* __restrict__ Wk0, const void* __restrict__ bk0,
    const void* __restrict__ Wk1, const void* __restrict__ bk1,
    const void* __restrict__ Wv0, const void* __restrict__ bv0,
    const void* __restrict__ Wv1, const void* __restrict__ bv1,
    u16* __restrict__ ws16) {
    const u32 fl = detect_bf16_fast((const u32*)x);
    const int z = blockIdx.z;
    const void* W; const void* bi;
    switch (z) {
        case 0:  W = Wq;  bi = bq;  break;
        case 1:  W = Wk0; bi = bk0; break;
        case 2:  W = Wk1; bi = bk1; break;
        case 3:  W = Wv0; bi = bv0; break;
        default: W = Wv1; bi = bv1; break;
    }
    proj_lds(x, fl, W, bi, fl, (void*)(ws16 + (size_t)z * TSZ), 1, 1u);
}

__global__ __launch_bounds__(256) void projo_kernel(const u16* __restrict__ ws16,
                                                    const void* __restrict__ Wo,
                                                    const void* __restrict__ bo,
                                                    void* __restrict__ out,
                                                    const void* __restrict__ xorig) {
    const u32 fl = detect_bf16_fast((const u32*)xorig);
    proj_lds(ws16 + OFF_ATT, 1u, Wo, bo, fl, out, 0, fl);
}

// ---------------------------------------------------------------------------
// MFMA attention, r16: r14 structure + kf software pipeline.
// r15 post-mortem: occupancy is PINNED at ~26-28% regardless of VGPR (60-84)
// and LDS (25-41KB) -> it is not a static-resource limit; VGPRs buy ILP here,
// not occupancy. r15's forced VGPR=60 serialized in-flight loads (MfmaUtil
// 22->15, VALUBusy 41->27, dur 58->83). So: back to 4-wave/84-VGPR r14
// structure and SPEND registers on latency hiding:
//  - kfA/kfB double-buffer (named arrays, static indices -- rule #20): issue
//    mt+1's k1 global loads (L2 ~250cy) before running mt's body, taking them
//    off the kf->GEMM1->exp->GEMM2 serial chain.
//  - b2 ds_read_b128 hoisted to top of body (~120cy hides under GEMM1+exp).
// Register-resident P via m-permutation folded into v1t staging (r14),
// barrier-free mt loop, swizzled v1t all unchanged.
// LDS 25600B: v1t [64 d][200] swz; epilogue osum (1KB) overlays after bar.
// ---------------------------------------------------------------------------
__global__ __launch_bounds__(256) void attn_kernel(u16* __restrict__ ws16) {
    __shared__ __align__(16) u16 smem[12800];   // 25600 B
    const int tid = threadIdx.x;
    const int w = tid >> 6, lane = tid & 63;
    const int quad = lane >> 4, li = lane & 15;
    const int k = blockIdx.x, bh = blockIdx.y;

    const u16* qg  = ws16 + ((size_t)bh * TT + k) * DD;
    const u16* k0g = ws16 + TSZ     + (size_t)bh * TT * DD;
    const u16* k1g = ws16 + 2 * TSZ + (size_t)bh * TT * DD;
    const u16* v0g = ws16 + 3 * TSZ + (size_t)bh * TT * DD;
    const u16* v1g = ws16 + 4 * TSZ + (size_t)bh * TT * DD;

    // ---- stage v1^T (stride 200, conflict swz (pos>>3)^(d>>3)) with the
    //      K-slot permutation folded into the row->position map ----
    //      v1 row m -> pos = (m&~31) | {m3,m2,m4,m1,m0}
#pragma unroll
    for (int it = 0; it < 6; it++) {
        const int flat = (it * 256 + tid) * 8;
        const int row = flat >> 6, c0 = flat & 63;   // row=m, c0=d base
        uint4 b = *(const uint4*)(v1g + flat);
        u16 vb[8]; *(uint4*)vb = b;
        const int w5 = row & 31;
        const int pos = (row & ~31) | ((w5 & 12) << 1) | ((w5 >> 4) << 2) | (w5 & 3);
        const int swz = (((pos >> 3) ^ (c0 >> 3)) << 3) | (pos & 7);
#pragma unroll
        for (int j = 0; j < 8; j++)
            smem[(c0 + j) * 200 + swz] = vb[j];
    }

    // ---- afr: a[l,d] = bf16_trunc(scl*q[d]*k0[l,d]), scl=0.125*log2e ----
    FragU afr[3][2];
#pragma unroll
    for (int kk = 0; kk < 2; kk++) {
        uint4 qu = *(const uint4*)(qg + kk * 32 + quad * 8);
        u16 qv[8]; *(uint4*)qv = qu;
        float qf[8];
#pragma unroll
        for (int j = 0; j < 8; j++) qf[j] = bf2f(qv[j]) * 0.18033688f;
#pragma unroll
        for (int rt = 0; rt < 3; rt++) {
            uint4 ku = *(const uint4*)(k0g + (size_t)(w * 48 + rt * 16 + li) * DD + kk * 32 + quad * 8);
            u16 kv[8]; *(uint4*)kv = ku;
            u32 pk[4];
#pragma unroll
            for (int p = 0; p < 4; p++) {
                u32 lo = __float_as_uint(qf[2 * p] * bf2f(kv[2 * p]));
                u32 hi = __float_as_uint(qf[2 * p + 1] * bf2f(kv[2 * p + 1]));
                pk[p] = trunc_pk(hi, lo);
            }
            afr[rt][kk].u = make_uint4(pk[0], pk[1], pk[2], pk[3]);
        }
    }

    FragU ones;
    ones.u = make_uint4(0x3F803F80u, 0x3F803F80u, 0x3F803F80u, 0x3F803F80u);

    f32x4 Wacc[3][4], Zacc[3];
#pragma unroll
    for (int rt = 0; rt < 3; rt++) {
        Zacc[rt] = (f32x4){0.f, 0.f, 0.f, 0.f};
#pragma unroll
        for (int cd = 0; cd < 4; cd++) Wacc[rt][cd] = (f32x4){0.f, 0.f, 0.f, 0.f};
    }

    // kf loader: 4 x global_load_dwordx4 of k1 rows for one 32-m tile.
    auto loadkf = [&](FragU (&kf)[2][2], int mt) {
#pragma unroll
        for (int ct = 0; ct < 2; ct++) {
            const u16* krow = k1g + (size_t)(mt * 32 + ct * 16 + li) * DD + quad * 8;
            kf[ct][0].u = *(const uint4*)(krow);
            kf[ct][1].u = *(const uint4*)(krow + 32);
        }
    };

    // per-m-tile body: GEMM1 (transposed) + v_exp_f32 packed straight into
    // A-frags + GEMM2/Z on MFMA pipe. b2 reads issued first (latency hides
    // under GEMM1+exp). All frag indices compile-time (rule #20).
    auto body = [&](const FragU (&kf)[2][2], int mt) {
        FragU b2[4];
#pragma unroll
        for (int cd = 0; cd < 4; cd++) {
            const int d = cd * 16 + li;
            b2[cd].u = *(const uint4*)(smem + d * 200 + (((mt * 4 + quad) ^ (d >> 3)) << 3));
        }
        FragU a2[3];
#pragma unroll
        for (int ct = 0; ct < 2; ct++) {
#pragma unroll
            for (int rt = 0; rt < 3; rt++) {
                f32x4 acc = (f32x4){0.f, 0.f, 0.f, 0.f};
                acc = __builtin_amdgcn_mfma_f32_16x16x32_bf16(kf[ct][0].b, afr[rt][0].b, acc, 0, 0, 0);
                acc = __builtin_amdgcn_mfma_f32_16x16x32_bf16(kf[ct][1].b, afr[rt][1].b, acc, 0, 0, 0);
                const u32 lo = trunc_pk(__float_as_uint(EXP2F(acc[1])), __float_as_uint(EXP2F(acc[0])));
                const u32 hi = trunc_pk(__float_as_uint(EXP2F(acc[3])), __float_as_uint(EXP2F(acc[2])));
                if (ct == 0) { a2[rt].u.x = lo; a2[rt].u.y = hi; }
                else         { a2[rt].u.z = lo; a2[rt].u.w = hi; }
            }
        }
#pragma unroll
        for (int rt = 0; rt < 3; rt++) {
            Zacc[rt] = __builtin_amdgcn_mfma_f32_16x16x32_bf16(a2[rt].b, ones.b, Zacc[rt], 0, 0, 0);
#pragma unroll
            for (int cd = 0; cd < 4; cd++)
                Wacc[rt][cd] = __builtin_amdgcn_mfma_f32_16x16x32_bf16(a2[rt].b, b2[cd].b, Wacc[rt][cd], 0, 0, 0);
        }
    };

    FragU kfA[2][2], kfB[2][2];
    loadkf(kfA, 0);      // issue before the staging barrier: lands under it

    __syncthreads();     // v1t staged

    // ---- m-tile loop (6 x 32), barrier-free, software-pipelined kf ----
    for (int mt2 = 0; mt2 < 3; mt2++) {
        loadkf(kfB, 2 * mt2 + 1);       // prefetch odd tile
        body(kfA, 2 * mt2);
        if (mt2 < 2) loadkf(kfA, 2 * mt2 + 2);   // prefetch next even tile
        body(kfB, 2 * mt2 + 1);
    }

    __syncthreads();   // all waves done with v1t (osum overlays it)

    // ---- epilogue: v0 from global, per-rt to cap live VGPRs ----
    float op[4] = {0.f, 0.f, 0.f, 0.f};
#pragma unroll
    for (int rt = 0; rt < 3; rt++) {
        float v0v[4][4];
#pragma unroll
        for (int r = 0; r < 4; r++) {
            const int l = w * 48 + rt * 16 + quad * 4 + r;
#pragma unroll
            for (int cd = 0; cd < 4; cd++)
                v0v[r][cd] = bf2f(v0g[(size_t)l * DD + cd * 16 + li]);
        }
#pragma unroll
        for (int r = 0; r < 4; r++) {
            const float iv = RCPF(Zacc[rt][r]);
#pragma unroll
            for (int cd = 0; cd < 4; cd++)
                op[cd] = fmaf(v0v[r][cd] * iv, Wacc[rt][cd][r], op[cd]);
        }
    }
#pragma unroll
    for (int cd = 0; cd < 4; cd++) {
        op[cd] += __shfl_xor(op[cd], 16);
        op[cd] += __shfl_xor(op[cd], 32);
    }
    float* osum = (float*)smem;
    if (quad == 0) {
#pragma unroll
        for (int cd = 0; cd < 4; cd++) osum[w * 64 + cd * 16 + li] = op[cd];
    }
    __syncthreads();
    if (tid < DD) {
        const float o = osum[tid] + osum[64 + tid] + osum[128 + tid] + osum[192 + tid];
        const int b = bh >> 3, h = bh & 7;
        u16* ATT = ws16 + OFF_ATT;
        ATT[((size_t)(b * TT + k)) * CC + h * DD + tid] = f2bf(o);
    }
}

extern "C" void kernel_launch(void* const* d_in, const int* in_sizes, int n_in,
                              void* d_out, int out_size, void* d_ws, size_t ws_size,
                              hipStream_t stream) {
    u16* ws16 = (u16*)d_ws;

    dim3 gp(CC / 64, MM / 64, 5);   // 8 x 6 x 5
    proj5_kernel<<<gp, 256, 0, stream>>>(
        d_in[0], d_in[1], d_in[2], d_in[3], d_in[4], d_in[5], d_in[6],
        d_in[7], d_in[8], d_in[9], d_in[10], ws16);

    dim3 ga(TT, BB * HH);           // 192 x 16, one k per block
    attn_kernel<<<ga, 256, 0, stream>>>(ws16);

    dim3 go(CC / 64, MM / 64, 1);   // 8 x 6
    projo_kernel<<<go, 256, 0, stream>>>(ws16, d_in[11], d_in[12], d_out, d_in[0]);
}

// Round 4
// 136.081 us; speedup vs baseline: 1.3120x; 1.1330x over previous
//
#include <hip/hip_runtime.h>
#include <hip/hip_bf16.h>

typedef unsigned short u16;
typedef unsigned int u32;

#define TT 192
#define BB 2
#define HH 8
#define DD 64
#define CC 512
#define MM (BB*TT)   // 384
#define KG 6         // k-values per attention block

// ws layout (u16 elements): Q,K0,K1,V0,V1 each [bh][t][d], then ATT [m][c]
#define TSZ   ((size_t)MM * CC)
#define OFF_ATT (5 * TSZ)

typedef short bf16x8 __attribute__((ext_vector_type(8)));
typedef float f32x4  __attribute__((ext_vector_type(4)));

union FragU { uint4 u; bf16x8 b; };

// Raw HW transcendentals (r13-verified: VALUBusy 58->27%)
#if __has_builtin(__builtin_amdgcn_exp2f)
#define EXP2F(x) __builtin_amdgcn_exp2f(x)
#else
#define EXP2F(x) exp2f(x)
#endif
#if __has_builtin(__builtin_amdgcn_rcpf)
#define RCPF(x) __builtin_amdgcn_rcpf(x)
#else
#define RCPF(x) (1.f / (x))
#endif

__device__ __forceinline__ float bf2f(u16 u) {
    return __uint_as_float(((u32)u) << 16);
}
__device__ __forceinline__ u16 f2bf(float f) {
    u32 u = __float_as_uint(f);
    u32 r = u + 0x7FFFu + ((u >> 16) & 1u);   // RNE
    return (u16)(r >> 16);
}
// pack hi16(a),hi16(b) -> one u32 (truncation round; bias cancels in P/Z)
__device__ __forceinline__ u32 trunc_pk(u32 b_hi, u32 a_lo) {
    return __builtin_amdgcn_perm(b_hi, a_lo, 0x07060302u);
}

// dtype detect: 1 load + ballot. bf16 data => low u16 exponent near 127.
__device__ __forceinline__ u32 detect_bf16_fast(const u32* __restrict__ x) {
    const int lane = threadIdx.x & 63;
    u32 v = x[lane & 31];
    u32 e = (v >> 7) & 0xFF;
    unsigned long long m = __ballot(e >= 113 && e <= 133);
    return (__popcll(m) >= 32) ? 1u : 0u;
}

// dtype-aware 16-element load (two uint4 of packed bf16)
__device__ __forceinline__ void ld16(const void* __restrict__ base, size_t off, u32 fl,
                                     uint4& lo, uint4& hi) {
    if (fl) {
        const uint4* p = (const uint4*)((const u16*)base + off);
        lo = p[0]; hi = p[1];
    } else {
        const float* s = (const float*)base + off;
        float4 f0 = *(const float4*)(s);
        float4 f1 = *(const float4*)(s + 4);
        float4 f2 = *(const float4*)(s + 8);
        float4 f3 = *(const float4*)(s + 12);
        lo = make_uint4((u32)f2bf(f0.x) | ((u32)f2bf(f0.y) << 16),
                        (u32)f2bf(f0.z) | ((u32)f2bf(f0.w) << 16),
                        (u32)f2bf(f1.x) | ((u32)f2bf(f1.y) << 16),
                        (u32)f2bf(f1.z) | ((u32)f2bf(f1.w) << 16));
        hi = make_uint4((u32)f2bf(f2.x) | ((u32)f2bf(f2.y) << 16),
                        (u32)f2bf(f2.z) | ((u32)f2bf(f2.w) << 16),
                        (u32)f2bf(f3.x) | ((u32)f2bf(f3.y) << 16),
                        (u32)f2bf(f3.z) | ((u32)f2bf(f3.w) << 16));
    }
}

// ---------------------------------------------------------------------------
// LDS-staged MFMA projection GEMM (r9-verified): out = A @ W^T + bias.
// ---------------------------------------------------------------------------
__device__ __forceinline__ void proj_lds(const void* __restrict__ A, u32 aFl,
                                         const void* __restrict__ W,
                                         const void* __restrict__ bias, u32 wFl,
                                         void* __restrict__ out, int headperm, u32 outFl) {
    __shared__ __align__(16) u16 As[64][72];
    __shared__ __align__(16) u16 Ws[64][72];
    const int tid = threadIdx.x;
    const int w = tid >> 6, lane = tid & 63;
    const int quad = lane >> 4, li = lane & 15;
    const int mb = blockIdx.y * 64, nb = blockIdx.x * 64;

    const int r = tid >> 2;
    const int c = (tid & 3) * 16;

    const size_t abase = (size_t)(mb + r) * CC + c;
    const size_t wbase = (size_t)(nb + r) * CC + c;

    f32x4 acc[4];
#pragma unroll
    for (int ct = 0; ct < 4; ct++) acc[ct] = (f32x4){0.f, 0.f, 0.f, 0.f};

    uint4 a0, a1, w0, w1;
    ld16(A, abase, aFl, a0, a1);
    ld16(W, wbase, wFl, w0, w1);

#pragma unroll
    for (int step = 0; step < 8; step++) {
        *(uint4*)&As[r][c] = a0; *(uint4*)&As[r][c + 8] = a1;
        *(uint4*)&Ws[r][c] = w0; *(uint4*)&Ws[r][c + 8] = w1;
        __syncthreads();
        if (step < 7) {
            const int kb = (step + 1) * 64;
            ld16(A, abase + kb, aFl, a0, a1);
            ld16(W, wbase + kb, wFl, w0, w1);
        }
#pragma unroll
        for (int kk = 0; kk < 2; kk++) {
            FragU af; af.u = *(const uint4*)&As[w * 16 + li][kk * 32 + quad * 8];
#pragma unroll
            for (int ct = 0; ct < 4; ct++) {
                FragU wf; wf.u = *(const uint4*)&Ws[ct * 16 + li][kk * 32 + quad * 8];
                acc[ct] = __builtin_amdgcn_mfma_f32_16x16x32_bf16(af.b, wf.b, acc[ct], 0, 0, 0);
            }
        }
        __syncthreads();
    }

#pragma unroll
    for (int ct = 0; ct < 4; ct++) {
        const int n = nb + ct * 16 + li;
        const float bv = wFl ? bf2f(((const u16*)bias)[n]) : ((const float*)bias)[n];
#pragma unroll
        for (int rr = 0; rr < 4; rr++) {
            const int m = mb + w * 16 + quad * 4 + rr;
            const float v = acc[ct][rr] + bv;
            if (headperm) {
                const int b = (m >= TT) ? 1 : 0;
                const int tloc = m - b * TT;
                ((u16*)out)[((size_t)(b * HH + (n >> 6)) * TT + tloc) * DD + (n & 63)] = f2bf(v);
            } else {
                if (outFl) ((u16*)out)[(size_t)m * CC + n] = f2bf(v);
                else       ((float*)out)[(size_t)m * CC + n] = v;
            }
        }
    }
}

__global__ __launch_bounds__(256) void proj5_kernel(
    const void* __restrict__ x,
    const void* __restrict__ Wq,  const void* __restrict__ bq,
    const void* __restrict__ Wk0, const void* __restrict__ bk0,
    const void* __restrict__ Wk1, const void* __restrict__ bk1,
    const void* __restrict__ Wv0, const void* __restrict__ bv0,
    const void* __restrict__ Wv1, const void* __restrict__ bv1,
    u16* __restrict__ ws16) {
    const u32 fl = detect_bf16_fast((const u32*)x);
    const int z = blockIdx.z;
    const void* W; const void* bi;
    switch (z) {
        case 0:  W = Wq;  bi = bq;  break;
        case 1:  W = Wk0; bi = bk0; break;
        case 2:  W = Wk1; bi = bk1; break;
        case 3:  W = Wv0; bi = bv0; break;
        default: W = Wv1; bi = bv1; break;
    }
    proj_lds(x, fl, W, bi, fl, (void*)(ws16 + (size_t)z * TSZ), 1, 1u);
}

__global__ __launch_bounds__(256) void projo_kernel(const u16* __restrict__ ws16,
                                                    const void* __restrict__ Wo,
                                                    const void* __restrict__ bo,
                                                    void* __restrict__ out,
                                                    const void* __restrict__ xorig) {
    const u32 fl = detect_bf16_fast((const u32*)xorig);
    proj_lds(ws16 + OFF_ATT, 1u, Wo, bo, fl, out, 0, fl);
}

// ---------------------------------------------------------------------------
// MFMA attention, r17: multi-k blocks + LDS-resident k1.
// r16 post-mortem: mt-loop was already fully unrolled/hoisted; with 84 arch
// VGPRs (+~60 AGPR acc) the compiler CANNOT keep 24 in-flight global k1
// loads -> serialized vmcnt batches; every wave re-reads k1 (24KB) from
// global, 4x redundant per block, 3072 blocks. Fix the stream, not the
// schedule:
//  - Block = (bh, 6 k's): grid 32x16 = 512 blocks = exactly 2/CU.
//  - k1 staged ONCE in LDS, XOR-swizzled (byte ^= (row&7)<<4, G4): kf reads
//    become conflict-free ds_read_b128 (~120cy, 2 outstanding suffice).
//  - v1t staging (r14 scatter + m-permutation) amortized 6x.
//  - k0 fragments are k-invariant: hoisted to registers once per block.
//  - k loop SEQUENTIAL, accumulators fresh per k (no VGPR growth -- r13's
//    parallel-k mistake avoided).
//  - osum: separate parity-double-buffered LDS (no overlay), 1 barrier/k.
// LDS: k1L 24576 + v1t 25600 + osum 2048 = 52224 B -> 2 blocks/CU (grid-
// limited anyway). Register-resident P (r14) unchanged.
// Matrix floor: 2 waves/SIMD x 972 MFMA x 19.4cy = 15.7us.
// ---------------------------------------------------------------------------
__global__ __launch_bounds__(256) void attn_kernel(u16* __restrict__ ws16) {
    __shared__ __align__(16) u16 k1L[TT * DD];      // 24576 B, XOR-swizzled
    __shared__ __align__(16) u16 v1t[DD * 200];     // 25600 B, r14 layout
    __shared__ float osum[2][256];                  // 2048 B, parity dbuf
    const int tid = threadIdx.x;
    const int w = tid >> 6, lane = tid & 63;
    const int quad = lane >> 4, li = lane & 15;
    const int kbase = blockIdx.x * KG, bh = blockIdx.y;

    const u16* qg0 = ws16 + ((size_t)bh * TT) * DD;
    const u16* k0g = ws16 + TSZ     + (size_t)bh * TT * DD;
    const u16* k1g = ws16 + 2 * TSZ + (size_t)bh * TT * DD;
    const u16* v0g = ws16 + 3 * TSZ + (size_t)bh * TT * DD;
    const u16* v1g = ws16 + 4 * TSZ + (size_t)bh * TT * DD;

    // ---- stage k1 (row-major, XOR swizzle: elem-col ^= (row&7)<<3) ----
#pragma unroll
    for (int it = 0; it < 6; it++) {
        const int flat = (it * 256 + tid) * 8;
        const int row = flat >> 6, c0 = flat & 63;
        uint4 b = *(const uint4*)(k1g + flat);
        *(uint4*)&k1L[row * DD + (c0 ^ ((row & 7) << 3))] = b;
    }

    // ---- stage v1^T (stride 200, conflict swz (pos>>3)^(d>>3)) with the
    //      K-slot permutation folded in: v1 row m -> pos bits {m3,m2,m4,m1,m0}
#pragma unroll
    for (int it = 0; it < 6; it++) {
        const int flat = (it * 256 + tid) * 8;
        const int row = flat >> 6, c0 = flat & 63;   // row=m, c0=d base
        uint4 b = *(const uint4*)(v1g + flat);
        u16 vb[8]; *(uint4*)vb = b;
        const int w5 = row & 31;
        const int pos = (row & ~31) | ((w5 & 12) << 1) | ((w5 >> 4) << 2) | (w5 & 3);
        const int swz = (((pos >> 3) ^ (c0 >> 3)) << 3) | (pos & 7);
#pragma unroll
        for (int j = 0; j < 8; j++)
            v1t[(c0 + j) * 200 + swz] = vb[j];
    }

    // ---- k-invariant k0 fragments (raw bf16, used to build afr per k) ----
    FragU k0f[3][2];
#pragma unroll
    for (int kk = 0; kk < 2; kk++)
#pragma unroll
        for (int rt = 0; rt < 3; rt++)
            k0f[rt][kk].u = *(const uint4*)(k0g + (size_t)(w * 48 + rt * 16 + li) * DD + kk * 32 + quad * 8);

    FragU ones;
    ones.u = make_uint4(0x3F803F80u, 0x3F803F80u, 0x3F803F80u, 0x3F803F80u);

    __syncthreads();   // k1L + v1t staged

    // ================= sequential k loop (6 k's per block) =================
#pragma unroll 1
    for (int kk6 = 0; kk6 < KG; kk6++) {
        const int k = kbase + kk6;

        // ---- afr: a[l,d] = bf16_trunc(scl*q[d]*k0[l,d]), scl=0.125*log2e ----
        FragU afr[3][2];
#pragma unroll
        for (int kk = 0; kk < 2; kk++) {
            uint4 qu = *(const uint4*)(qg0 + (size_t)k * DD + kk * 32 + quad * 8);
            u16 qv[8]; *(uint4*)qv = qu;
            float qf[8];
#pragma unroll
            for (int j = 0; j < 8; j++) qf[j] = bf2f(qv[j]) * 0.18033688f;
#pragma unroll
            for (int rt = 0; rt < 3; rt++) {
                u16 kv[8]; *(uint4*)kv = k0f[rt][kk].u;
                u32 pk[4];
#pragma unroll
                for (int p = 0; p < 4; p++) {
                    u32 lo = __float_as_uint(qf[2 * p] * bf2f(kv[2 * p]));
                    u32 hi = __float_as_uint(qf[2 * p + 1] * bf2f(kv[2 * p + 1]));
                    pk[p] = trunc_pk(hi, lo);
                }
                afr[rt][kk].u = make_uint4(pk[0], pk[1], pk[2], pk[3]);
            }
        }

        f32x4 Wacc[3][4], Zacc[3];
#pragma unroll
        for (int rt = 0; rt < 3; rt++) {
            Zacc[rt] = (f32x4){0.f, 0.f, 0.f, 0.f};
#pragma unroll
            for (int cd = 0; cd < 4; cd++) Wacc[rt][cd] = (f32x4){0.f, 0.f, 0.f, 0.f};
        }

        // ---- m-tile loop (6 x 32), barrier-free; kf from swizzled LDS ----
#pragma unroll
        for (int mt = 0; mt < 6; mt++) {
            FragU a2[3];
#pragma unroll
            for (int ct = 0; ct < 2; ct++) {
                const int r0 = mt * 32 + ct * 16 + li;
                const int sw = (r0 & 7) << 3;
                FragU kf0, kf1;
                kf0.u = *(const uint4*)&k1L[r0 * DD + ((quad * 8) ^ sw)];
                kf1.u = *(const uint4*)&k1L[r0 * DD + ((32 + quad * 8) ^ sw)];
#pragma unroll
                for (int rt = 0; rt < 3; rt++) {
                    f32x4 acc = (f32x4){0.f, 0.f, 0.f, 0.f};
                    acc = __builtin_amdgcn_mfma_f32_16x16x32_bf16(kf0.b, afr[rt][0].b, acc, 0, 0, 0);
                    acc = __builtin_amdgcn_mfma_f32_16x16x32_bf16(kf1.b, afr[rt][1].b, acc, 0, 0, 0);
                    const u32 lo = trunc_pk(__float_as_uint(EXP2F(acc[1])), __float_as_uint(EXP2F(acc[0])));
                    const u32 hi = trunc_pk(__float_as_uint(EXP2F(acc[3])), __float_as_uint(EXP2F(acc[2])));
                    if (ct == 0) { a2[rt].u.x = lo; a2[rt].u.y = hi; }
                    else         { a2[rt].u.z = lo; a2[rt].u.w = hi; }
                }
            }
            FragU b2[4];
#pragma unroll
            for (int cd = 0; cd < 4; cd++) {
                const int d = cd * 16 + li;
                b2[cd].u = *(const uint4*)&v1t[d * 200 + (((mt * 4 + quad) ^ (d >> 3)) << 3)];
            }
#pragma unroll
            for (int rt = 0; rt < 3; rt++) {
                Zacc[rt] = __builtin_amdgcn_mfma_f32_16x16x32_bf16(a2[rt].b, ones.b, Zacc[rt], 0, 0, 0);
#pragma unroll
                for (int cd = 0; cd < 4; cd++)
                    Wacc[rt][cd] = __builtin_amdgcn_mfma_f32_16x16x32_bf16(a2[rt].b, b2[cd].b, Wacc[rt][cd], 0, 0, 0);
            }
        }

        // ---- epilogue: v0 from global (L2-hot), per-rt to cap live VGPRs ----
        float op[4] = {0.f, 0.f, 0.f, 0.f};
#pragma unroll
        for (int rt = 0; rt < 3; rt++) {
            float v0v[4][4];
#pragma unroll
            for (int r = 0; r < 4; r++) {
                const int l = w * 48 + rt * 16 + quad * 4 + r;
#pragma unroll
                for (int cd = 0; cd < 4; cd++)
                    v0v[r][cd] = bf2f(v0g[(size_t)l * DD + cd * 16 + li]);
            }
#pragma unroll
            for (int r = 0; r < 4; r++) {
                const float iv = RCPF(Zacc[rt][r]);
#pragma unroll
                for (int cd = 0; cd < 4; cd++)
                    op[cd] = fmaf(v0v[r][cd] * iv, Wacc[rt][cd][r], op[cd]);
            }
        }
#pragma unroll
        for (int cd = 0; cd < 4; cd++) {
            op[cd] += __shfl_xor(op[cd], 16);
            op[cd] += __shfl_xor(op[cd], 32);
        }
        float* os = osum[kk6 & 1];
        if (quad == 0) {
#pragma unroll
            for (int cd = 0; cd < 4; cd++) os[w * 64 + cd * 16 + li] = op[cd];
        }
        __syncthreads();
        if (tid < DD) {
            const float o = os[tid] + os[64 + tid] + os[128 + tid] + os[192 + tid];
            const int b = bh >> 3, h = bh & 7;
            u16* ATT = ws16 + OFF_ATT;
            ATT[((size_t)(b * TT + k)) * CC + h * DD + tid] = f2bf(o);
        }
    }
}

extern "C" void kernel_launch(void* const* d_in, const int* in_sizes, int n_in,
                              void* d_out, int out_size, void* d_ws, size_t ws_size,
                              hipStream_t stream) {
    u16* ws16 = (u16*)d_ws;

    dim3 gp(CC / 64, MM / 64, 5);   // 8 x 6 x 5
    proj5_kernel<<<gp, 256, 0, stream>>>(
        d_in[0], d_in[1], d_in[2], d_in[3], d_in[4], d_in[5], d_in[6],
        d_in[7], d_in[8], d_in[9], d_in[10], ws16);

    dim3 ga(TT / KG, BB * HH);      // 32 x 16, six k per block
    attn_kernel<<<ga, 256, 0, stream>>>(ws16);

    dim3 go(CC / 64, MM / 64, 1);   // 8 x 6
    projo_kernel<<<go, 256, 0, stream>>>(ws16, d_in[11], d_in[12], d_out, d_in[0]);
}